// Round 3
// baseline (199.587 us; speedup 1.0000x reference)
//
#include <hip/hip_runtime.h>

// Problem constants (fixed by setup_inputs): B=128, BANDS=256, P=32, K=64
#define SIGMA 0.1f
#define BANDS 256
#define KSEL  64
#define PPB   4      // planes (b,j pairs) per block; 4 divides KSEL so all share b

// Fused kernel: every block redundantly computes the top-64 selection
// (cheap: 256 gates, rank via LDS-broadcast loop), then gathers+scales its
// 4 assigned output planes. One graph node, no inter-kernel dependency.
//
// Selection semantics == jax.lax.top_k + jnp.sort(idx): band t is selected
// iff fewer than K bands beat it (higher gate, or equal gate with lower
// index); selected bands are emitted in ascending band order.
__global__ void __launch_bounds__(BANDS)
FeatureSelector_fused(const float4* __restrict__ x,
                      const float*  __restrict__ mu,
                      const float*  __restrict__ noise,
                      const float*  __restrict__ extra,
                      float4*       __restrict__ out) {
    __shared__ float g[BANDS];
    __shared__ unsigned long long masks[BANDS / 64];
    __shared__ int   lds_idx[KSEL];
    __shared__ float lds_gate[KSEL];

    const int tid  = threadIdx.x;
    const int wave = tid >> 6;
    const int lane = tid & 63;

    // --- gate compute (one band per thread) ---
    float z = mu[tid] + SIGMA * (noise[tid] + 0.25f * extra[tid]) + 0.5f;
    float gate = fminf(fmaxf(z, 0.0f), 1.0f);
    g[tid] = gate;
    __syncthreads();

    // --- rank: all threads scan the same g[j] (LDS broadcast, conflict-free)
    int rank = 0;
#pragma unroll 16
    for (int j = 0; j < BANDS; ++j) {
        float gj = g[j];
        rank += (gj > gate) || (gj == gate && j < tid);
    }
    const bool sel = rank < KSEL;

    unsigned long long m = __ballot(sel);
    if (lane == 0) masks[wave] = m;
    __syncthreads();

    if (sel) {
        int pos = __popcll(m & ((1ull << lane) - 1ull));
        for (int w = 0; w < wave; ++w) pos += __popcll(masks[w]);
        lds_idx[pos]  = tid;      // ascending band order == jnp.sort(idx)
        lds_gate[pos] = gate;
    }
    __syncthreads();

    // --- gather + scale: PPB planes per block, all sharing batch b ---
    const int bj0 = blockIdx.x * PPB;
    const int b   = bj0 >> 6;            // / KSEL
    const int j0  = bj0 & (KSEL - 1);

    int   band[PPB];
    float s[PPB];
#pragma unroll
    for (int p = 0; p < PPB; ++p) {
        band[p] = lds_idx[j0 + p];
        s[p]    = lds_gate[j0 + p];
    }

    float4 v[PPB];
#pragma unroll
    for (int p = 0; p < PPB; ++p)
        v[p] = x[(b * BANDS + band[p]) * 256 + tid];
#pragma unroll
    for (int p = 0; p < PPB; ++p) {
        v[p].x *= s[p]; v[p].y *= s[p]; v[p].z *= s[p]; v[p].w *= s[p];
        out[(b * KSEL + j0 + p) * 256 + tid] = v[p];
    }
}

extern "C" void kernel_launch(void* const* d_in, const int* in_sizes, int n_in,
                              void* d_out, int out_size, void* d_ws, size_t ws_size,
                              hipStream_t stream) {
    const float* x     = (const float*)d_in[0];  // (128,1,256,32,32)
    const float* mu    = (const float*)d_in[1];  // (256,)
    const float* noise = (const float*)d_in[2];  // (256,)
    const float* extra = (const float*)d_in[3];  // (256,)
    // d_in[4] = k (=64), hard-coded as KSEL

    const int B = 128;
    FeatureSelector_fused<<<(B * KSEL) / PPB, BANDS, 0, stream>>>(
        (const float4*)x, mu, noise, extra, (float4*)d_out);
}

// Round 5
// 190.014 us; speedup vs baseline: 1.0504x; 1.0504x over previous
//
#include <hip/hip_runtime.h>

// Problem constants (fixed by setup_inputs): B=128, BANDS=256, P=32, K=64
#define SIGMA 0.1f
#define BANDS 256
#define KSEL  64
#define GTHREADS 512   // gather block size
#define PPB      8     // planes per gather block (8 divides KSEL -> same b)

typedef float vfloat4 __attribute__((ext_vector_type(4)));  // native vec for nontemporal builtins

// Kernel 1: compute gates, select top-64 (jax.lax.top_k tie-break: lower
// index wins on equal values), emit indices sorted ascending + gathered gate
// values into workspace. Runs once; gather blocks consume ws.
__global__ void FeatureSelector_topk(const float* __restrict__ mu,
                                     const float* __restrict__ noise,
                                     const float* __restrict__ extra,
                                     int*   __restrict__ ws_idx,
                                     float* __restrict__ ws_gate) {
    __shared__ float g[BANDS];
    __shared__ unsigned long long masks[BANDS / 64];
    const int tid  = threadIdx.x;
    const int wave = tid >> 6;
    const int lane = tid & 63;

    float z = mu[tid] + SIGMA * (noise[tid] + 0.25f * extra[tid]) + 0.5f;
    float gate = fminf(fmaxf(z, 0.0f), 1.0f);
    g[tid] = gate;
    __syncthreads();

    // rank = number of elements that beat me (higher value, or equal value
    // with lower index). rank < K  =>  selected.
    int rank = 0;
#pragma unroll 16
    for (int j = 0; j < BANDS; ++j) {
        float gj = g[j];
        rank += (gj > gate) || (gj == gate && j < tid);
    }
    const bool sel = rank < KSEL;

    unsigned long long m = __ballot(sel);
    if (lane == 0) masks[wave] = m;
    __syncthreads();

    if (sel) {
        int pos = __popcll(m & ((1ull << lane) - 1ull));
        for (int w = 0; w < wave; ++w) pos += __popcll(masks[w]);
        ws_idx[pos]  = tid;     // ascending band order == jnp.sort(idx)
        ws_gate[pos] = gate;
    }
}

// Kernel 2: out[b, j, :, :] = x[b, idx[j], :, :] * gate[idx[j]]
// 512 threads handle 2 planes per "slot"; PPB=8 planes per block.
// Each thread: 8/2 = 4 float4 loads in flight, non-temporal (stream-once).
__global__ void __launch_bounds__(GTHREADS)
FeatureSelector_gather(const vfloat4* __restrict__ x,
                       const int*     __restrict__ ws_idx,
                       const float*   __restrict__ ws_gate,
                       vfloat4*       __restrict__ out) {
    const int bj0 = blockIdx.x * PPB;     // first (b,j) of this block
    const int b   = bj0 >> 6;             // / KSEL
    const int j0  = bj0 & (KSEL - 1);
    const int tid = threadIdx.x;          // 0..511: covers 2 planes per step
    const int jt  = tid >> 8;             // which of the 2 planes in a step
    const int t   = tid & 255;            // float4 index within plane

    constexpr int STEPS = PPB / 2;        // 4

    int   band[STEPS];
    float s[STEPS];
#pragma unroll
    for (int p = 0; p < STEPS; ++p) {
        band[p] = ws_idx[j0 + 2 * p + jt];
        s[p]    = ws_gate[j0 + 2 * p + jt];
    }

    vfloat4 v[STEPS];
#pragma unroll
    for (int p = 0; p < STEPS; ++p)
        v[p] = __builtin_nontemporal_load(&x[(b * BANDS + band[p]) * 256 + t]);
#pragma unroll
    for (int p = 0; p < STEPS; ++p) {
        v[p] *= s[p];
        __builtin_nontemporal_store(v[p], &out[(b * KSEL + j0 + 2 * p + jt) * 256 + t]);
    }
}

extern "C" void kernel_launch(void* const* d_in, const int* in_sizes, int n_in,
                              void* d_out, int out_size, void* d_ws, size_t ws_size,
                              hipStream_t stream) {
    const float* x     = (const float*)d_in[0];  // (128,1,256,32,32)
    const float* mu    = (const float*)d_in[1];  // (256,)
    const float* noise = (const float*)d_in[2];  // (256,)
    const float* extra = (const float*)d_in[3];  // (256,)
    // d_in[4] = k (=64), hard-coded as KSEL

    int*   ws_idx  = (int*)d_ws;
    float* ws_gate = (float*)((char*)d_ws + KSEL * sizeof(int));

    FeatureSelector_topk<<<1, BANDS, 0, stream>>>(mu, noise, extra, ws_idx, ws_gate);

    const int B = 128;
    FeatureSelector_gather<<<(B * KSEL) / PPB, GTHREADS, 0, stream>>>(
        (const vfloat4*)x, ws_idx, ws_gate, (vfloat4*)d_out);
}